// Round 12
// baseline (557.675 us; speedup 1.0000x reference)
//
#include <hip/hip_runtime.h>
#include <hip/hip_bf16.h>

#define NNODES 100000
#define NEDGES 1600000
#define NR     100096   // 782 * 128, padded row count for GEMM tiles
#define NGRAPH 512
#define NB     782      // buckets of 128 dst nodes
#define NBLK_BIN 128    // blocks in hist/scatter passes
#define EPB    12500    // edges per bin block = NEDGES / NBLK_BIN

typedef __attribute__((ext_vector_type(8))) __bf16 bf16x8;
typedef __attribute__((ext_vector_type(4))) float f32x4;
typedef __attribute__((ext_vector_type(4))) unsigned int u32x4;
typedef __attribute__((ext_vector_type(2))) unsigned int u32x2;

__device__ __forceinline__ float b2f(unsigned int u16) {
    union { float f; unsigned int i; } v; v.i = (u16 & 0xffffu) << 16; return v.f;
}
__device__ __forceinline__ unsigned short f2b(float f) {
    union { float f; unsigned int i; } v; v.f = f;
    unsigned int u = (v.i + 0x7fffu + ((v.i >> 16) & 1u)) >> 16;
    return (unsigned short)u;
}

// ---------------- weights f32 -> bf16 (once per launch) ----------------
// Wb layout (bf16 elems): t1w @0, t2w @16384, W1[l] @32768+l*16384, W2[l] @81920+l*16384
__global__ __launch_bounds__(256) void wconv(const float* __restrict__ t1w,
                                             const float* __restrict__ t2w,
                                             const float* __restrict__ W1,
                                             const float* __restrict__ W2,
                                             unsigned short* __restrict__ Wb) {
    int i = blockIdx.x * 256 + threadIdx.x;   // float4 index, 32768 total
    float4 v;
    if (i < 4096)       v = reinterpret_cast<const float4*>(t1w)[i];
    else if (i < 8192)  v = reinterpret_cast<const float4*>(t2w)[i - 4096];
    else if (i < 20480) v = reinterpret_cast<const float4*>(W1)[i - 8192];
    else                v = reinterpret_cast<const float4*>(W2)[i - 20480];
    u32x2 o;
    o.x = (unsigned int)f2b(v.x) | ((unsigned int)f2b(v.y) << 16);
    o.y = (unsigned int)f2b(v.z) | ((unsigned int)f2b(v.w) << 16);
    *reinterpret_cast<u32x2*>(Wb + (size_t)i * 4) = o;
}

// ---------------- two-pass radix partition by dst bucket (no global atomics) ----------------
__global__ __launch_bounds__(256) void hist_k(const int* __restrict__ dst,
                                              int* __restrict__ ghist) {
    __shared__ int lh[NB];
    int blk = blockIdx.x, tid = threadIdx.x;
    for (int i = tid; i < NB; i += 256) lh[i] = 0;
    __syncthreads();
    int s = blk * EPB;
    for (int i = s + tid; i < s + EPB; i += 256) atomicAdd(&lh[dst[i] >> 7], 1);
    __syncthreads();
    for (int b = tid; b < NB; b += 256) ghist[b * NBLK_BIN + blk] = lh[b];
}

// per-bucket exclusive scan over the 128 block counts (one wave per bucket)
__global__ __launch_bounds__(256) void scan_pairs(const int* __restrict__ ghist,
                                                  int* __restrict__ off,
                                                  int* __restrict__ tot) {
    int wid = threadIdx.x >> 6, lane = threadIdx.x & 63;
    int b = blockIdx.x * 4 + wid;
    if (b >= NB) return;
    int v0 = ghist[b * NBLK_BIN + lane * 2];
    int v1 = ghist[b * NBLK_BIN + lane * 2 + 1];
    int s = v0 + v1, incl = s;
    for (int o = 1; o < 64; o <<= 1) {
        int t = __shfl_up(incl, o);
        if (lane >= o) incl += t;
    }
    int excl = incl - s;
    off[b * NBLK_BIN + lane * 2] = excl;
    off[b * NBLK_BIN + lane * 2 + 1] = excl + v0;
    if (lane == 63) tot[b] = incl;
}

__global__ __launch_bounds__(1024) void boff_scan(const int* __restrict__ tot,
                                                  int* __restrict__ boff) {
    __shared__ int sm[1024];
    int t = threadIdx.x;
    int v = (t < NB) ? tot[t] : 0;
    sm[t] = v;
    __syncthreads();
    for (int o = 1; o < 1024; o <<= 1) {
        int u = (t >= o) ? sm[t - o] : 0;
        __syncthreads();
        sm[t] += u;
        __syncthreads();
    }
    if (t < NB) boff[t] = sm[t] - v;
    if (t == NB - 1) boff[NB] = sm[t];
}

__global__ __launch_bounds__(256) void scatter2(const int* __restrict__ src,
                                                const int* __restrict__ dst,
                                                const int* __restrict__ off,
                                                const int* __restrict__ boff,
                                                unsigned int* __restrict__ binned) {
    __shared__ int lbase[NB];
    __shared__ int lcnt[NB];
    int blk = blockIdx.x, tid = threadIdx.x;
    for (int b = tid; b < NB; b += 256) {
        lbase[b] = boff[b] + off[b * NBLK_BIN + blk];
        lcnt[b] = 0;
    }
    __syncthreads();
    int s0 = blk * EPB;
    for (int i = s0 + tid; i < s0 + EPB; i += 256) {
        int d = dst[i];
        int b = d >> 7;
        int r = atomicAdd(&lcnt[b], 1);
        binned[lbase[b] + r] = (unsigned int)src[i] | ((unsigned int)(d & 127) << 17);
    }
}

__global__ __launch_bounds__(256) void csr_build(const int* __restrict__ boff,
                                                 const unsigned int* __restrict__ binned,
                                                 int* __restrict__ rowptr,
                                                 int* __restrict__ csr) {
    __shared__ int lhist[128], lscan[128], lcnt[128];
    int b = blockIdx.x, tid = threadIdx.x;
    int s = boff[b], e = boff[b + 1];
    if (tid < 128) { lhist[tid] = 0; lcnt[tid] = 0; }
    __syncthreads();
    for (int i = s + tid; i < e; i += 256)
        atomicAdd(&lhist[(binned[i] >> 17) & 127], 1);
    __syncthreads();
    if (tid < 128) lscan[tid] = lhist[tid];
    __syncthreads();
    for (int o = 1; o < 128; o <<= 1) {
        int v = (tid < 128 && tid >= o) ? lscan[tid - o] : 0;
        __syncthreads();
        if (tid < 128) lscan[tid] += v;
        __syncthreads();
    }
    if (tid < 128) {
        int n = b * 128 + tid;
        if (n <= NNODES) rowptr[n] = s + lscan[tid] - lhist[tid];
    }
    __syncthreads();
    for (int i = s + tid; i < e; i += 256) {
        unsigned int v = binned[i];
        int dl = (v >> 17) & 127;
        int r = atomicAdd(&lcnt[dl], 1);
        csr[s + lscan[dl] - lhist[dl] + r] = (int)(v & 0x1FFFFu);
    }
}

// ---------------- fused GIN layer: gather + MLP (2 GEMMs) per 128-node bucket ----------------
// Block b owns nodes [b*128, b*128+128). 512 threads = 8 waves.
// Phase G: wave w gathers z for nodes w*16..w*16+15 (register accum, bf16 -> swizzled LDS).
// Phase 1: y = relu(bn(z @ W1^T + b1)) -> back into the same LDS tile; W2 restaged.
// Phase 2: h = y @ W2^T + b2 -> global.
__global__ __launch_bounds__(512) void layer_fused(const unsigned short* __restrict__ hPrev,
                                                   const int* __restrict__ rowptr,
                                                   const int* __restrict__ csr,
                                                   const unsigned short* __restrict__ W1b,
                                                   const unsigned short* __restrict__ W2b,
                                                   const float* __restrict__ b1,
                                                   const float* __restrict__ gamma,
                                                   const float* __restrict__ beta,
                                                   const float* __restrict__ b2,
                                                   unsigned short* __restrict__ hNext) {
    __shared__ unsigned short lsZ[128 * 128];
    __shared__ unsigned short lsB[128 * 128];
    const int tid = threadIdx.x;
    const int w = tid >> 6;
    const int lane = tid & 63;
    const int nodeBase = blockIdx.x * 128;
    const int g  = lane >> 4;
    const int fl = lane & 15;

    // stage W1 (bf16, swizzled) — overlaps with gather loads
#pragma unroll
    for (int it = 0; it < 4; ++it) {
        int idx = it * 512 + tid;
        int row = idx >> 4, u = idx & 15;
        uint4 v = *reinterpret_cast<const uint4*>(W1b + (size_t)row * 128 + u * 8);
        *reinterpret_cast<uint4*>((char*)lsB + row * 256 + ((u * 16) ^ ((row & 7) << 4))) = v;
    }

    // ---- gather phase ----
    for (int nl = 0; nl < 16; ++nl) {
        const int lr = w * 16 + nl;            // local row 0..127
        const int node = nodeBase + lr;
        float a0 = 0.f, a1 = 0.f, a2 = 0.f, a3 = 0.f, a4 = 0.f, a5 = 0.f, a6 = 0.f, a7 = 0.f;
        int s = 0, e = 0;
        if (node < NNODES) { s = rowptr[node]; e = rowptr[node + 1]; }
        int i = s + g;
        for (; i + 12 < e; i += 16) {
            int j0 = csr[i];
            int j1 = csr[i + 4];
            int j2 = csr[i + 8];
            int j3 = csr[i + 12];
            u32x4 v0 = *reinterpret_cast<const u32x4*>(hPrev + (size_t)j0 * 128 + fl * 8);
            u32x4 v1 = *reinterpret_cast<const u32x4*>(hPrev + (size_t)j1 * 128 + fl * 8);
            u32x4 v2 = *reinterpret_cast<const u32x4*>(hPrev + (size_t)j2 * 128 + fl * 8);
            u32x4 v3 = *reinterpret_cast<const u32x4*>(hPrev + (size_t)j3 * 128 + fl * 8);
            a0 += b2f(v0.x); a1 += b2f(v0.x >> 16);
            a2 += b2f(v0.y); a3 += b2f(v0.y >> 16);
            a4 += b2f(v0.z); a5 += b2f(v0.z >> 16);
            a6 += b2f(v0.w); a7 += b2f(v0.w >> 16);
            a0 += b2f(v1.x); a1 += b2f(v1.x >> 16);
            a2 += b2f(v1.y); a3 += b2f(v1.y >> 16);
            a4 += b2f(v1.z); a5 += b2f(v1.z >> 16);
            a6 += b2f(v1.w); a7 += b2f(v1.w >> 16);
            a0 += b2f(v2.x); a1 += b2f(v2.x >> 16);
            a2 += b2f(v2.y); a3 += b2f(v2.y >> 16);
            a4 += b2f(v2.z); a5 += b2f(v2.z >> 16);
            a6 += b2f(v2.w); a7 += b2f(v2.w >> 16);
            a0 += b2f(v3.x); a1 += b2f(v3.x >> 16);
            a2 += b2f(v3.y); a3 += b2f(v3.y >> 16);
            a4 += b2f(v3.z); a5 += b2f(v3.z >> 16);
            a6 += b2f(v3.w); a7 += b2f(v3.w >> 16);
        }
        for (; i < e; i += 4) {
            int j0 = csr[i];
            u32x4 v0 = *reinterpret_cast<const u32x4*>(hPrev + (size_t)j0 * 128 + fl * 8);
            a0 += b2f(v0.x); a1 += b2f(v0.x >> 16);
            a2 += b2f(v0.y); a3 += b2f(v0.y >> 16);
            a4 += b2f(v0.z); a5 += b2f(v0.z >> 16);
            a6 += b2f(v0.w); a7 += b2f(v0.w >> 16);
        }
        a0 += __shfl_xor(a0, 16); a1 += __shfl_xor(a1, 16);
        a2 += __shfl_xor(a2, 16); a3 += __shfl_xor(a3, 16);
        a4 += __shfl_xor(a4, 16); a5 += __shfl_xor(a5, 16);
        a6 += __shfl_xor(a6, 16); a7 += __shfl_xor(a7, 16);
        a0 += __shfl_xor(a0, 32); a1 += __shfl_xor(a1, 32);
        a2 += __shfl_xor(a2, 32); a3 += __shfl_xor(a3, 32);
        a4 += __shfl_xor(a4, 32); a5 += __shfl_xor(a5, 32);
        a6 += __shfl_xor(a6, 32); a7 += __shfl_xor(a7, 32);
        if (g == 0) {
            u32x4 sv = *reinterpret_cast<const u32x4*>(hPrev + (size_t)node * 128 + fl * 8);
            a0 += b2f(sv.x); a1 += b2f(sv.x >> 16);
            a2 += b2f(sv.y); a3 += b2f(sv.y >> 16);
            a4 += b2f(sv.z); a5 += b2f(sv.z >> 16);
            a6 += b2f(sv.w); a7 += b2f(sv.w >> 16);
            u32x4 o;
            o.x = (unsigned int)f2b(a0) | ((unsigned int)f2b(a1) << 16);
            o.y = (unsigned int)f2b(a2) | ((unsigned int)f2b(a3) << 16);
            o.z = (unsigned int)f2b(a4) | ((unsigned int)f2b(a5) << 16);
            o.w = (unsigned int)f2b(a6) | ((unsigned int)f2b(a7) << 16);
            *reinterpret_cast<u32x4*>((char*)lsZ + lr * 256 + ((fl * 16) ^ ((lr & 7) << 4))) = o;
        }
    }
    __syncthreads();

    // ---- phase 1 MFMA: y = relu(bn(z @ W1^T + b1)) ----
    const int wr = w >> 1, wc = w & 1;   // 32-row x 64-col tile per wave
    f32x4 acc[2][4];
    f32x4 zv = {0.f, 0.f, 0.f, 0.f};
#pragma unroll
    for (int m = 0; m < 2; ++m)
#pragma unroll
        for (int n = 0; n < 4; ++n) acc[m][n] = zv;
#pragma unroll
    for (int ks = 0; ks < 4; ++ks) {
        int kbb = ks * 64 + ((lane >> 4) << 4);
        bf16x8 af[2], bfr[4];
#pragma unroll
        for (int m = 0; m < 2; ++m) {
            int ar = wr * 32 + m * 16 + (lane & 15);
            af[m] = *reinterpret_cast<const bf16x8*>((char*)lsZ + ar * 256 + (kbb ^ ((ar & 7) << 4)));
        }
#pragma unroll
        for (int n = 0; n < 4; ++n) {
            int bc = wc * 64 + n * 16 + (lane & 15);
            bfr[n] = *reinterpret_cast<const bf16x8*>((char*)lsB + bc * 256 + (kbb ^ ((bc & 7) << 4)));
        }
#pragma unroll
        for (int m = 0; m < 2; ++m)
#pragma unroll
            for (int n = 0; n < 4; ++n)
                acc[m][n] = __builtin_amdgcn_mfma_f32_16x16x32_bf16(af[m], bfr[n], acc[m][n], 0, 0, 0);
    }
    __syncthreads();   // all lsZ/lsB reads complete

    // write y back into lsZ (bf16, swizzled); restage lsB = W2
#pragma unroll
    for (int n = 0; n < 4; ++n) {
        int col = wc * 64 + n * 16 + (lane & 15);
        float bb = b1[col];
        float sc = gamma[col] * rsqrtf(1.0f + 1e-5f);
        float bt = beta[col];
#pragma unroll
        for (int m = 0; m < 2; ++m) {
            int r0 = wr * 32 + m * 16 + ((lane >> 4) << 2);
#pragma unroll
            for (int r = 0; r < 4; ++r) {
                float v = (acc[m][n][r] + bb) * sc + bt;
                v = fmaxf(v, 0.f);
                int row = r0 + r;
                *(unsigned short*)((char*)lsZ + row * 256 + ((2 * col) ^ ((row & 7) << 4))) = f2b(v);
            }
        }
    }
#pragma unroll
    for (int it = 0; it < 4; ++it) {
        int idx = it * 512 + tid;
        int row = idx >> 4, u = idx & 15;
        uint4 v = *reinterpret_cast<const uint4*>(W2b + (size_t)row * 128 + u * 8);
        *reinterpret_cast<uint4*>((char*)lsB + row * 256 + ((u * 16) ^ ((row & 7) << 4))) = v;
    }
    __syncthreads();

    // ---- phase 2 MFMA: h = y @ W2^T + b2 ----
    f32x4 acc2[2][4];
#pragma unroll
    for (int m = 0; m < 2; ++m)
#pragma unroll
        for (int n = 0; n < 4; ++n) acc2[m][n] = zv;
#pragma unroll
    for (int ks = 0; ks < 4; ++ks) {
        int kbb = ks * 64 + ((lane >> 4) << 4);
        bf16x8 af[2], bfr[4];
#pragma unroll
        for (int m = 0; m < 2; ++m) {
            int ar = wr * 32 + m * 16 + (lane & 15);
            af[m] = *reinterpret_cast<const bf16x8*>((char*)lsZ + ar * 256 + (kbb ^ ((ar & 7) << 4)));
        }
#pragma unroll
        for (int n = 0; n < 4; ++n) {
            int bc = wc * 64 + n * 16 + (lane & 15);
            bfr[n] = *reinterpret_cast<const bf16x8*>((char*)lsB + bc * 256 + (kbb ^ ((bc & 7) << 4)));
        }
#pragma unroll
        for (int m = 0; m < 2; ++m)
#pragma unroll
            for (int n = 0; n < 4; ++n)
                acc2[m][n] = __builtin_amdgcn_mfma_f32_16x16x32_bf16(af[m], bfr[n], acc2[m][n], 0, 0, 0);
    }

#pragma unroll
    for (int n = 0; n < 4; ++n) {
        int col = wc * 64 + n * 16 + (lane & 15);
        float bb = b2[col];
#pragma unroll
        for (int m = 0; m < 2; ++m) {
            int r0 = nodeBase + wr * 32 + m * 16 + ((lane >> 4) << 2);
#pragma unroll
            for (int r = 0; r < 4; ++r)
                hNext[(size_t)(r0 + r) * 128 + col] = f2b(acc2[m][n][r] + bb);
        }
    }
}

// ---------------- GEMM (LDS + swizzle), bf16 weights ----------------
// MODE: 0 = bias only, 1 = bias+relu
template <int SRC_F32, int MODE>
__global__ __launch_bounds__(256) void gemm128(const void* __restrict__ Asrc, int src_rows,
                                               const unsigned short* __restrict__ Wb,
                                               const float* __restrict__ bias,
                                               unsigned short* __restrict__ Out) {
    __shared__ unsigned short lsA[128 * 128];
    __shared__ unsigned short lsB[128 * 128];
    const int tid = threadIdx.x;
    const int blockRow = blockIdx.x * 128;

    for (int it = 0; it < 8; ++it) {
        int idx = it * 256 + tid;
        int row = idx >> 4;
        int u = idx & 15;
        uint4 v = *reinterpret_cast<const uint4*>(Wb + (size_t)row * 128 + u * 8);
        int boffb = row * 256 + ((u * 16) ^ ((row & 7) << 4));
        *reinterpret_cast<uint4*>((char*)lsB + boffb) = v;
    }
    if (SRC_F32) {
        const float* A = (const float*)Asrc;
        for (int it = 0; it < 16; ++it) {
            int fidx = it * 256 + tid;
            int row = fidx >> 5;
            int c4 = (fidx & 31) * 4;
            int gr = blockRow + row; if (gr > src_rows - 1) gr = src_rows - 1;
            float4 v = *reinterpret_cast<const float4*>(A + (size_t)gr * 128 + c4);
            int boffb = row * 256 + ((c4 * 2) ^ ((row & 7) << 4));
            unsigned short* p = (unsigned short*)((char*)lsA + boffb);
            p[0] = f2b(v.x); p[1] = f2b(v.y); p[2] = f2b(v.z); p[3] = f2b(v.w);
        }
    } else {
        const unsigned short* A = (const unsigned short*)Asrc;
        for (int it = 0; it < 8; ++it) {
            int idx = it * 256 + tid;
            int row = idx >> 4;
            int u = idx & 15;
            int gr = blockRow + row;        // padded buffer
            uint4 v = *reinterpret_cast<const uint4*>(A + (size_t)gr * 128 + u * 8);
            int boffb = row * 256 + ((u * 16) ^ ((row & 7) << 4));
            *reinterpret_cast<uint4*>((char*)lsA + boffb) = v;
        }
    }
    __syncthreads();

    const int lane = tid & 63;
    const int w = tid >> 6;
    const int wr = w >> 1, wc = w & 1;

    f32x4 acc[4][4];
    f32x4 zv = {0.f, 0.f, 0.f, 0.f};
#pragma unroll
    for (int m = 0; m < 4; ++m)
#pragma unroll
        for (int n = 0; n < 4; ++n) acc[m][n] = zv;

#pragma unroll
    for (int ks = 0; ks < 4; ++ks) {
        int kbb = ks * 64 + ((lane >> 4) << 4);
        bf16x8 af[4], bfr[4];
#pragma unroll
        for (int m = 0; m < 4; ++m) {
            int ar = wr * 64 + m * 16 + (lane & 15);
            af[m] = *reinterpret_cast<const bf16x8*>((char*)lsA + ar * 256 + (kbb ^ ((ar & 7) << 4)));
        }
#pragma unroll
        for (int n = 0; n < 4; ++n) {
            int bc = wc * 64 + n * 16 + (lane & 15);
            bfr[n] = *reinterpret_cast<const bf16x8*>((char*)lsB + bc * 256 + (kbb ^ ((bc & 7) << 4)));
        }
#pragma unroll
        for (int m = 0; m < 4; ++m)
#pragma unroll
            for (int n = 0; n < 4; ++n)
                acc[m][n] = __builtin_amdgcn_mfma_f32_16x16x32_bf16(af[m], bfr[n], acc[m][n], 0, 0, 0);
    }

#pragma unroll
    for (int n = 0; n < 4; ++n) {
        int col = wc * 64 + n * 16 + (lane & 15);
        float bb = bias[col];
#pragma unroll
        for (int m = 0; m < 4; ++m) {
            int r0 = blockRow + wr * 64 + m * 16 + ((lane >> 4) << 2);
#pragma unroll
            for (int r = 0; r < 4; ++r) {
                float v = acc[m][n][r] + bb;
                if (MODE >= 1) v = fmaxf(v, 0.f);
                Out[(size_t)(r0 + r) * 128 + col] = f2b(v);
            }
        }
    }
}

// ---------------- segment sum over sorted batch ----------------
__global__ __launch_bounds__(128) void segsum(const unsigned short* __restrict__ hf,
                                              const int* __restrict__ batch,
                                              float* __restrict__ out) {
    int g = blockIdx.x, f = threadIdx.x;
    int lo = 0, hi = NNODES;
    while (lo < hi) { int mid = (lo + hi) >> 1; if (batch[mid] < g) lo = mid + 1; else hi = mid; }
    int s = lo;
    lo = 0; hi = NNODES;
    while (lo < hi) { int mid = (lo + hi) >> 1; if (batch[mid] < g + 1) lo = mid + 1; else hi = mid; }
    int e = lo;
    float acc0 = 0.f, acc1 = 0.f, acc2 = 0.f, acc3 = 0.f;
    int n = s;
    for (; n + 3 < e; n += 4) {
        acc0 += b2f(hf[(size_t)n * 128 + f]);
        acc1 += b2f(hf[(size_t)(n + 1) * 128 + f]);
        acc2 += b2f(hf[(size_t)(n + 2) * 128 + f]);
        acc3 += b2f(hf[(size_t)(n + 3) * 128 + f]);
    }
    for (; n < e; ++n) acc0 += b2f(hf[(size_t)n * 128 + f]);
    out[(size_t)g * 128 + f] = (acc0 + acc1) + (acc2 + acc3);
}

extern "C" void kernel_launch(void* const* d_in, const int* in_sizes, int n_in,
                              void* d_out, int out_size, void* d_ws, size_t ws_size,
                              hipStream_t stream) {
    const float* x     = (const float*)d_in[0];
    const int*   ei    = (const int*)d_in[1];
    const int*   batch = (const int*)d_in[2];
    const float* t1w   = (const float*)d_in[3];
    const float* t1b   = (const float*)d_in[4];
    const float* t2w   = (const float*)d_in[5];
    const float* t2b   = (const float*)d_in[6];
    const float* W1    = (const float*)d_in[7];
    const float* b1    = (const float*)d_in[8];
    const float* gamma = (const float*)d_in[9];
    const float* beta  = (const float*)d_in[10];
    const float* W2    = (const float*)d_in[11];
    const float* b2    = (const float*)d_in[12];
    float* out = (float*)d_out;

    char* ws = (char*)d_ws;
    size_t off_b = 0;
    auto alloc = [&](size_t bytes) -> void* {
        off_b = (off_b + 511) & ~size_t(511);
        void* p = ws + off_b;
        off_b += bytes;
        return p;
    };
    unsigned short* hbA = (unsigned short*)alloc((size_t)NR * 128 * 2);
    unsigned short* hbB = (unsigned short*)alloc((size_t)NR * 128 * 2);
    unsigned short* Wb  = (unsigned short*)alloc((size_t)131072 * 2);
    int* rowptr         = (int*)alloc((size_t)(NNODES + 2) * 4);
    int* ghist          = (int*)alloc((size_t)NB * NBLK_BIN * 4);
    int* off            = (int*)alloc((size_t)NB * NBLK_BIN * 4);
    int* tot            = (int*)alloc((size_t)NB * 4);
    int* boff           = (int*)alloc((size_t)(NB + 1) * 4);
    unsigned int* binned = (unsigned int*)alloc((size_t)NEDGES * 4);
    int* csr            = (int*)alloc((size_t)NEDGES * 4);

    const int* esrc = ei;
    const int* edst = ei + NEDGES;

    // weights -> bf16
    wconv<<<128, 256, 0, stream>>>(t1w, t2w, W1, W2, Wb);

    // two-pass partition + CSR build (no global atomics)
    hist_k<<<NBLK_BIN, 256, 0, stream>>>(edst, ghist);
    scan_pairs<<<(NB + 3) / 4, 256, 0, stream>>>(ghist, off, tot);
    boff_scan<<<1, 1024, 0, stream>>>(tot, boff);
    scatter2<<<NBLK_BIN, 256, 0, stream>>>(esrc, edst, off, boff, binned);
    csr_build<<<NB, 256, 0, stream>>>(boff, binned, rowptr, csr);

    // h = relu(x @ t1_w^T + t1_b) -> hbA
    gemm128<1, 1><<<NR / 128, 256, 0, stream>>>(x, NNODES, Wb, t1b, hbA);

    // 3 fused GIN layers, ping-pong hbA <-> hbB
    const unsigned short* hin = hbA;
    unsigned short* hout = hbB;
    for (int l = 0; l < 3; ++l) {
        layer_fused<<<NB, 512, 0, stream>>>(hin, rowptr, csr,
                                            Wb + 32768 + (size_t)l * 16384,
                                            Wb + 81920 + (size_t)l * 16384,
                                            b1 + l * 128, gamma + l * 128, beta + l * 128,
                                            b2 + l * 128, hout);
        unsigned short* t = (unsigned short*)hin; hin = hout; hout = t;
    }
    // final transform (reads hin = hbB after 3 layers) -> hout buffer
    gemm128<0, 0><<<NR / 128, 256, 0, stream>>>(hin, NR, Wb + 16384, t2b, hout);
    segsum<<<NGRAPH, 128, 0, stream>>>(hout, batch, out);
}

// Round 13
// 459.352 us; speedup vs baseline: 1.2140x; 1.2140x over previous
//
#include <hip/hip_runtime.h>
#include <hip/hip_bf16.h>

#define NNODES 100000
#define NEDGES 1600000
#define NR     100096   // 782 * 128, padded row count for GEMM tiles
#define NGRAPH 512
#define NB     782      // buckets of 128 dst nodes
#define NBLK_BIN 128    // blocks in hist/scatter passes
#define EPB    12500    // edges per bin block = NEDGES / NBLK_BIN

typedef __attribute__((ext_vector_type(8))) __bf16 bf16x8;
typedef __attribute__((ext_vector_type(4))) float f32x4;
typedef __attribute__((ext_vector_type(4))) unsigned int u32x4;
typedef __attribute__((ext_vector_type(2))) unsigned int u32x2;

__device__ __forceinline__ float b2f(unsigned int u16) {
    union { float f; unsigned int i; } v; v.i = (u16 & 0xffffu) << 16; return v.f;
}
__device__ __forceinline__ unsigned short f2b(float f) {
    union { float f; unsigned int i; } v; v.f = f;
    unsigned int u = (v.i + 0x7fffu + ((v.i >> 16) & 1u)) >> 16;
    return (unsigned short)u;
}

// ---------------- weights f32 -> bf16 (once per launch) ----------------
// Wb layout (bf16 elems): t1w @0, t2w @16384, W1[l] @32768+l*16384, W2[l] @81920+l*16384
__global__ __launch_bounds__(256) void wconv(const float* __restrict__ t1w,
                                             const float* __restrict__ t2w,
                                             const float* __restrict__ W1,
                                             const float* __restrict__ W2,
                                             unsigned short* __restrict__ Wb) {
    int i = blockIdx.x * 256 + threadIdx.x;   // float4 index, 32768 total
    float4 v;
    if (i < 4096)       v = reinterpret_cast<const float4*>(t1w)[i];
    else if (i < 8192)  v = reinterpret_cast<const float4*>(t2w)[i - 4096];
    else if (i < 20480) v = reinterpret_cast<const float4*>(W1)[i - 8192];
    else                v = reinterpret_cast<const float4*>(W2)[i - 20480];
    u32x2 o;
    o.x = (unsigned int)f2b(v.x) | ((unsigned int)f2b(v.y) << 16);
    o.y = (unsigned int)f2b(v.z) | ((unsigned int)f2b(v.w) << 16);
    *reinterpret_cast<u32x2*>(Wb + (size_t)i * 4) = o;
}

// ---------------- two-pass radix partition by dst bucket (no global atomics) ----------------
__global__ __launch_bounds__(256) void hist_k(const int* __restrict__ dst,
                                              int* __restrict__ ghist) {
    __shared__ int lh[NB];
    int blk = blockIdx.x, tid = threadIdx.x;
    for (int i = tid; i < NB; i += 256) lh[i] = 0;
    __syncthreads();
    int s = blk * EPB;
    for (int i = s + tid; i < s + EPB; i += 256) atomicAdd(&lh[dst[i] >> 7], 1);
    __syncthreads();
    for (int b = tid; b < NB; b += 256) ghist[b * NBLK_BIN + blk] = lh[b];
}

// per-bucket exclusive scan over the 128 block counts (one wave per bucket)
__global__ __launch_bounds__(256) void scan_pairs(const int* __restrict__ ghist,
                                                  int* __restrict__ off,
                                                  int* __restrict__ tot) {
    int wid = threadIdx.x >> 6, lane = threadIdx.x & 63;
    int b = blockIdx.x * 4 + wid;
    if (b >= NB) return;
    int v0 = ghist[b * NBLK_BIN + lane * 2];
    int v1 = ghist[b * NBLK_BIN + lane * 2 + 1];
    int s = v0 + v1, incl = s;
    for (int o = 1; o < 64; o <<= 1) {
        int t = __shfl_up(incl, o);
        if (lane >= o) incl += t;
    }
    int excl = incl - s;
    off[b * NBLK_BIN + lane * 2] = excl;
    off[b * NBLK_BIN + lane * 2 + 1] = excl + v0;
    if (lane == 63) tot[b] = incl;
}

__global__ __launch_bounds__(1024) void boff_scan(const int* __restrict__ tot,
                                                  int* __restrict__ boff) {
    __shared__ int sm[1024];
    int t = threadIdx.x;
    int v = (t < NB) ? tot[t] : 0;
    sm[t] = v;
    __syncthreads();
    for (int o = 1; o < 1024; o <<= 1) {
        int u = (t >= o) ? sm[t - o] : 0;
        __syncthreads();
        sm[t] += u;
        __syncthreads();
    }
    if (t < NB) boff[t] = sm[t] - v;
    if (t == NB - 1) boff[NB] = sm[t];
}

__global__ __launch_bounds__(256) void scatter2(const int* __restrict__ src,
                                                const int* __restrict__ dst,
                                                const int* __restrict__ off,
                                                const int* __restrict__ boff,
                                                unsigned int* __restrict__ binned) {
    __shared__ int lbase[NB];
    __shared__ int lcnt[NB];
    int blk = blockIdx.x, tid = threadIdx.x;
    for (int b = tid; b < NB; b += 256) {
        lbase[b] = boff[b] + off[b * NBLK_BIN + blk];
        lcnt[b] = 0;
    }
    __syncthreads();
    int s0 = blk * EPB;
    for (int i = s0 + tid; i < s0 + EPB; i += 256) {
        int d = dst[i];
        int b = d >> 7;
        int r = atomicAdd(&lcnt[b], 1);
        binned[lbase[b] + r] = (unsigned int)src[i] | ((unsigned int)(d & 127) << 17);
    }
}

__global__ __launch_bounds__(256) void csr_build(const int* __restrict__ boff,
                                                 const unsigned int* __restrict__ binned,
                                                 int* __restrict__ rowptr,
                                                 int* __restrict__ csr) {
    __shared__ int lhist[128], lscan[128], lcnt[128];
    int b = blockIdx.x, tid = threadIdx.x;
    int s = boff[b], e = boff[b + 1];
    if (tid < 128) { lhist[tid] = 0; lcnt[tid] = 0; }
    __syncthreads();
    for (int i = s + tid; i < e; i += 256)
        atomicAdd(&lhist[(binned[i] >> 17) & 127], 1);
    __syncthreads();
    if (tid < 128) lscan[tid] = lhist[tid];
    __syncthreads();
    for (int o = 1; o < 128; o <<= 1) {
        int v = (tid < 128 && tid >= o) ? lscan[tid - o] : 0;
        __syncthreads();
        if (tid < 128) lscan[tid] += v;
        __syncthreads();
    }
    if (tid < 128) {
        int n = b * 128 + tid;
        if (n <= NNODES) rowptr[n] = s + lscan[tid] - lhist[tid];
    }
    __syncthreads();
    for (int i = s + tid; i < e; i += 256) {
        unsigned int v = binned[i];
        int dl = (v >> 17) & 127;
        int r = atomicAdd(&lcnt[dl], 1);
        csr[s + lscan[dl] - lhist[dl] + r] = (int)(v & 0x1FFFFu);
    }
}

// ---------------- aggregation: z[i] = h[i] + sum_{j->i} h[j]  (bf16 out) ----------------
// One node per wave; 16 row-loads in flight (4 lane-groups x unroll 4).
__global__ __launch_bounds__(256) void agg_node4(const unsigned short* __restrict__ hb,
                                                 const int* __restrict__ rowptr,
                                                 const int* __restrict__ csr,
                                                 unsigned short* __restrict__ zb) {
    int wid = threadIdx.x >> 6, lane = threadIdx.x & 63;
    int node = blockIdx.x * 4 + wid;
    if (node >= NNODES) return;
    const int g  = lane >> 4;
    const int fl = lane & 15;

    float a0 = 0.f, a1 = 0.f, a2 = 0.f, a3 = 0.f, a4 = 0.f, a5 = 0.f, a6 = 0.f, a7 = 0.f;
    const int s = rowptr[node], e = rowptr[node + 1];

    int i = s + g;
    for (; i + 12 < e; i += 16) {
        int j0 = csr[i];
        int j1 = csr[i + 4];
        int j2 = csr[i + 8];
        int j3 = csr[i + 12];
        u32x4 v0 = *reinterpret_cast<const u32x4*>(hb + (size_t)j0 * 128 + fl * 8);
        u32x4 v1 = *reinterpret_cast<const u32x4*>(hb + (size_t)j1 * 128 + fl * 8);
        u32x4 v2 = *reinterpret_cast<const u32x4*>(hb + (size_t)j2 * 128 + fl * 8);
        u32x4 v3 = *reinterpret_cast<const u32x4*>(hb + (size_t)j3 * 128 + fl * 8);
        a0 += b2f(v0.x); a1 += b2f(v0.x >> 16);
        a2 += b2f(v0.y); a3 += b2f(v0.y >> 16);
        a4 += b2f(v0.z); a5 += b2f(v0.z >> 16);
        a6 += b2f(v0.w); a7 += b2f(v0.w >> 16);
        a0 += b2f(v1.x); a1 += b2f(v1.x >> 16);
        a2 += b2f(v1.y); a3 += b2f(v1.y >> 16);
        a4 += b2f(v1.z); a5 += b2f(v1.z >> 16);
        a6 += b2f(v1.w); a7 += b2f(v1.w >> 16);
        a0 += b2f(v2.x); a1 += b2f(v2.x >> 16);
        a2 += b2f(v2.y); a3 += b2f(v2.y >> 16);
        a4 += b2f(v2.z); a5 += b2f(v2.z >> 16);
        a6 += b2f(v2.w); a7 += b2f(v2.w >> 16);
        a0 += b2f(v3.x); a1 += b2f(v3.x >> 16);
        a2 += b2f(v3.y); a3 += b2f(v3.y >> 16);
        a4 += b2f(v3.z); a5 += b2f(v3.z >> 16);
        a6 += b2f(v3.w); a7 += b2f(v3.w >> 16);
    }
    for (; i < e; i += 4) {
        int j0 = csr[i];
        u32x4 v0 = *reinterpret_cast<const u32x4*>(hb + (size_t)j0 * 128 + fl * 8);
        a0 += b2f(v0.x); a1 += b2f(v0.x >> 16);
        a2 += b2f(v0.y); a3 += b2f(v0.y >> 16);
        a4 += b2f(v0.z); a5 += b2f(v0.z >> 16);
        a6 += b2f(v0.w); a7 += b2f(v0.w >> 16);
    }

    a0 += __shfl_xor(a0, 16); a1 += __shfl_xor(a1, 16);
    a2 += __shfl_xor(a2, 16); a3 += __shfl_xor(a3, 16);
    a4 += __shfl_xor(a4, 16); a5 += __shfl_xor(a5, 16);
    a6 += __shfl_xor(a6, 16); a7 += __shfl_xor(a7, 16);
    a0 += __shfl_xor(a0, 32); a1 += __shfl_xor(a1, 32);
    a2 += __shfl_xor(a2, 32); a3 += __shfl_xor(a3, 32);
    a4 += __shfl_xor(a4, 32); a5 += __shfl_xor(a5, 32);
    a6 += __shfl_xor(a6, 32); a7 += __shfl_xor(a7, 32);

    if (g == 0) {
        u32x4 sv = *reinterpret_cast<const u32x4*>(hb + (size_t)node * 128 + fl * 8);
        a0 += b2f(sv.x); a1 += b2f(sv.x >> 16);
        a2 += b2f(sv.y); a3 += b2f(sv.y >> 16);
        a4 += b2f(sv.z); a5 += b2f(sv.z >> 16);
        a6 += b2f(sv.w); a7 += b2f(sv.w >> 16);
        u32x4 o;
        o.x = (unsigned int)f2b(a0) | ((unsigned int)f2b(a1) << 16);
        o.y = (unsigned int)f2b(a2) | ((unsigned int)f2b(a3) << 16);
        o.z = (unsigned int)f2b(a4) | ((unsigned int)f2b(a5) << 16);
        o.w = (unsigned int)f2b(a6) | ((unsigned int)f2b(a7) << 16);
        *reinterpret_cast<u32x4*>(zb + (size_t)node * 128 + fl * 8) = o;
    }
}

// ---------------- fused MLP: h = (relu(bn(z@W1^T+b1)))@W2^T + b2 ----------------
// Pure-GEMM kernel (no gather): 512 threads, z-tile + W in LDS, y never leaves LDS.
__global__ __launch_bounds__(512) void mlp128(const unsigned short* __restrict__ zb,
                                              const unsigned short* __restrict__ W1b,
                                              const unsigned short* __restrict__ W2b,
                                              const float* __restrict__ b1,
                                              const float* __restrict__ gamma,
                                              const float* __restrict__ beta,
                                              const float* __restrict__ b2,
                                              unsigned short* __restrict__ hNext) {
    __shared__ unsigned short lsZ[128 * 128];
    __shared__ unsigned short lsB[128 * 128];
    const int tid = threadIdx.x;
    const int w = tid >> 6;
    const int lane = tid & 63;
    const int blockRow = blockIdx.x * 128;

    // stage z tile (bf16, swizzled) and W1
#pragma unroll
    for (int it = 0; it < 4; ++it) {
        int idx = it * 512 + tid;           // 2048 16B-units
        int row = idx >> 4, u = idx & 15;
        uint4 v = *reinterpret_cast<const uint4*>(zb + (size_t)(blockRow + row) * 128 + u * 8);
        *reinterpret_cast<uint4*>((char*)lsZ + row * 256 + ((u * 16) ^ ((row & 7) << 4))) = v;
    }
#pragma unroll
    for (int it = 0; it < 4; ++it) {
        int idx = it * 512 + tid;
        int row = idx >> 4, u = idx & 15;
        uint4 v = *reinterpret_cast<const uint4*>(W1b + (size_t)row * 128 + u * 8);
        *reinterpret_cast<uint4*>((char*)lsB + row * 256 + ((u * 16) ^ ((row & 7) << 4))) = v;
    }
    __syncthreads();

    // phase 1: y = relu(bn(z @ W1^T + b1)), per-wave 32x64 tile
    const int wr = w >> 1, wc = w & 1;
    f32x4 acc[2][4];
    f32x4 zv = {0.f, 0.f, 0.f, 0.f};
#pragma unroll
    for (int m = 0; m < 2; ++m)
#pragma unroll
        for (int n = 0; n < 4; ++n) acc[m][n] = zv;
#pragma unroll
    for (int ks = 0; ks < 4; ++ks) {
        int kbb = ks * 64 + ((lane >> 4) << 4);
        bf16x8 af[2], bfr[4];
#pragma unroll
        for (int m = 0; m < 2; ++m) {
            int ar = wr * 32 + m * 16 + (lane & 15);
            af[m] = *reinterpret_cast<const bf16x8*>((char*)lsZ + ar * 256 + (kbb ^ ((ar & 7) << 4)));
        }
#pragma unroll
        for (int n = 0; n < 4; ++n) {
            int bc = wc * 64 + n * 16 + (lane & 15);
            bfr[n] = *reinterpret_cast<const bf16x8*>((char*)lsB + bc * 256 + (kbb ^ ((bc & 7) << 4)));
        }
#pragma unroll
        for (int m = 0; m < 2; ++m)
#pragma unroll
            for (int n = 0; n < 4; ++n)
                acc[m][n] = __builtin_amdgcn_mfma_f32_16x16x32_bf16(af[m], bfr[n], acc[m][n], 0, 0, 0);
    }
    __syncthreads();   // all lsZ/lsB reads complete before overwrite

    // write y back into lsZ (bf16, swizzled); restage lsB = W2
#pragma unroll
    for (int n = 0; n < 4; ++n) {
        int col = wc * 64 + n * 16 + (lane & 15);
        float bb = b1[col];
        float sc = gamma[col] * rsqrtf(1.0f + 1e-5f);
        float bt = beta[col];
#pragma unroll
        for (int m = 0; m < 2; ++m) {
            int r0 = wr * 32 + m * 16 + ((lane >> 4) << 2);
#pragma unroll
            for (int r = 0; r < 4; ++r) {
                float v = (acc[m][n][r] + bb) * sc + bt;
                v = fmaxf(v, 0.f);
                int row = r0 + r;
                *(unsigned short*)((char*)lsZ + row * 256 + ((2 * col) ^ ((row & 7) << 4))) = f2b(v);
            }
        }
    }
#pragma unroll
    for (int it = 0; it < 4; ++it) {
        int idx = it * 512 + tid;
        int row = idx >> 4, u = idx & 15;
        uint4 v = *reinterpret_cast<const uint4*>(W2b + (size_t)row * 128 + u * 8);
        *reinterpret_cast<uint4*>((char*)lsB + row * 256 + ((u * 16) ^ ((row & 7) << 4))) = v;
    }
    __syncthreads();

    // phase 2: h = y @ W2^T + b2
    f32x4 acc2[2][4];
#pragma unroll
    for (int m = 0; m < 2; ++m)
#pragma unroll
        for (int n = 0; n < 4; ++n) acc2[m][n] = zv;
#pragma unroll
    for (int ks = 0; ks < 4; ++ks) {
        int kbb = ks * 64 + ((lane >> 4) << 4);
        bf16x8 af[2], bfr[4];
#pragma unroll
        for (int m = 0; m < 2; ++m) {
            int ar = wr * 32 + m * 16 + (lane & 15);
            af[m] = *reinterpret_cast<const bf16x8*>((char*)lsZ + ar * 256 + (kbb ^ ((ar & 7) << 4)));
        }
#pragma unroll
        for (int n = 0; n < 4; ++n) {
            int bc = wc * 64 + n * 16 + (lane & 15);
            bfr[n] = *reinterpret_cast<const bf16x8*>((char*)lsB + bc * 256 + (kbb ^ ((bc & 7) << 4)));
        }
#pragma unroll
        for (int m = 0; m < 2; ++m)
#pragma unroll
            for (int n = 0; n < 4; ++n)
                acc2[m][n] = __builtin_amdgcn_mfma_f32_16x16x32_bf16(af[m], bfr[n], acc2[m][n], 0, 0, 0);
    }

#pragma unroll
    for (int n = 0; n < 4; ++n) {
        int col = wc * 64 + n * 16 + (lane & 15);
        float bb = b2[col];
#pragma unroll
        for (int m = 0; m < 2; ++m) {
            int r0 = blockRow + wr * 32 + m * 16 + ((lane >> 4) << 2);
#pragma unroll
            for (int r = 0; r < 4; ++r)
                hNext[(size_t)(r0 + r) * 128 + col] = f2b(acc2[m][n][r] + bb);
        }
    }
}

// ---------------- GEMM (LDS + swizzle), bf16 weights ----------------
// MODE: 0 = bias only, 1 = bias+relu
template <int SRC_F32, int MODE>
__global__ __launch_bounds__(256) void gemm128(const void* __restrict__ Asrc, int src_rows,
                                               const unsigned short* __restrict__ Wb,
                                               const float* __restrict__ bias,
                                               unsigned short* __restrict__ Out) {
    __shared__ unsigned short lsA[128 * 128];
    __shared__ unsigned short lsB[128 * 128];
    const int tid = threadIdx.x;
    const int blockRow = blockIdx.x * 128;

    for (int it = 0; it < 8; ++it) {
        int idx = it * 256 + tid;
        int row = idx >> 4;
        int u = idx & 15;
        uint4 v = *reinterpret_cast<const uint4*>(Wb + (size_t)row * 128 + u * 8);
        int boffb = row * 256 + ((u * 16) ^ ((row & 7) << 4));
        *reinterpret_cast<uint4*>((char*)lsB + boffb) = v;
    }
    if (SRC_F32) {
        const float* A = (const float*)Asrc;
        for (int it = 0; it < 16; ++it) {
            int fidx = it * 256 + tid;
            int row = fidx >> 5;
            int c4 = (fidx & 31) * 4;
            int gr = blockRow + row; if (gr > src_rows - 1) gr = src_rows - 1;
            float4 v = *reinterpret_cast<const float4*>(A + (size_t)gr * 128 + c4);
            int boffb = row * 256 + ((c4 * 2) ^ ((row & 7) << 4));
            unsigned short* p = (unsigned short*)((char*)lsA + boffb);
            p[0] = f2b(v.x); p[1] = f2b(v.y); p[2] = f2b(v.z); p[3] = f2b(v.w);
        }
    } else {
        const unsigned short* A = (const unsigned short*)Asrc;
        for (int it = 0; it < 8; ++it) {
            int idx = it * 256 + tid;
            int row = idx >> 4;
            int u = idx & 15;
            int gr = blockRow + row;        // padded buffer
            uint4 v = *reinterpret_cast<const uint4*>(A + (size_t)gr * 128 + u * 8);
            int boffb = row * 256 + ((u * 16) ^ ((row & 7) << 4));
            *reinterpret_cast<uint4*>((char*)lsA + boffb) = v;
        }
    }
    __syncthreads();

    const int lane = tid & 63;
    const int w = tid >> 6;
    const int wr = w >> 1, wc = w & 1;

    f32x4 acc[4][4];
    f32x4 zv = {0.f, 0.f, 0.f, 0.f};
#pragma unroll
    for (int m = 0; m < 4; ++m)
#pragma unroll
        for (int n = 0; n < 4; ++n) acc[m][n] = zv;

#pragma unroll
    for (int ks = 0; ks < 4; ++ks) {
        int kbb = ks * 64 + ((lane >> 4) << 4);
        bf16x8 af[4], bfr[4];
#pragma unroll
        for (int m = 0; m < 4; ++m) {
            int ar = wr * 64 + m * 16 + (lane & 15);
            af[m] = *reinterpret_cast<const bf16x8*>((char*)lsA + ar * 256 + (kbb ^ ((ar & 7) << 4)));
        }
#pragma unroll
        for (int n = 0; n < 4; ++n) {
            int bc = wc * 64 + n * 16 + (lane & 15);
            bfr[n] = *reinterpret_cast<const bf16x8*>((char*)lsB + bc * 256 + (kbb ^ ((bc & 7) << 4)));
        }
#pragma unroll
        for (int m = 0; m < 4; ++m)
#pragma unroll
            for (int n = 0; n < 4; ++n)
                acc[m][n] = __builtin_amdgcn_mfma_f32_16x16x32_bf16(af[m], bfr[n], acc[m][n], 0, 0, 0);
    }

#pragma unroll
    for (int n = 0; n < 4; ++n) {
        int col = wc * 64 + n * 16 + (lane & 15);
        float bb = bias[col];
#pragma unroll
        for (int m = 0; m < 4; ++m) {
            int r0 = blockRow + wr * 64 + m * 16 + ((lane >> 4) << 2);
#pragma unroll
            for (int r = 0; r < 4; ++r) {
                float v = acc[m][n][r] + bb;
                if (MODE >= 1) v = fmaxf(v, 0.f);
                Out[(size_t)(r0 + r) * 128 + col] = f2b(v);
            }
        }
    }
}

// ---------------- segment sum over sorted batch ----------------
__global__ __launch_bounds__(128) void segsum(const unsigned short* __restrict__ hf,
                                              const int* __restrict__ batch,
                                              float* __restrict__ out) {
    int g = blockIdx.x, f = threadIdx.x;
    int lo = 0, hi = NNODES;
    while (lo < hi) { int mid = (lo + hi) >> 1; if (batch[mid] < g) lo = mid + 1; else hi = mid; }
    int s = lo;
    lo = 0; hi = NNODES;
    while (lo < hi) { int mid = (lo + hi) >> 1; if (batch[mid] < g + 1) lo = mid + 1; else hi = mid; }
    int e = lo;
    float acc0 = 0.f, acc1 = 0.f, acc2 = 0.f, acc3 = 0.f;
    int n = s;
    for (; n + 3 < e; n += 4) {
        acc0 += b2f(hf[(size_t)n * 128 + f]);
        acc1 += b2f(hf[(size_t)(n + 1) * 128 + f]);
        acc2 += b2f(hf[(size_t)(n + 2) * 128 + f]);
        acc3 += b2f(hf[(size_t)(n + 3) * 128 + f]);
    }
    for (; n < e; ++n) acc0 += b2f(hf[(size_t)n * 128 + f]);
    out[(size_t)g * 128 + f] = (acc0 + acc1) + (acc2 + acc3);
}

extern "C" void kernel_launch(void* const* d_in, const int* in_sizes, int n_in,
                              void* d_out, int out_size, void* d_ws, size_t ws_size,
                              hipStream_t stream) {
    const float* x     = (const float*)d_in[0];
    const int*   ei    = (const int*)d_in[1];
    const int*   batch = (const int*)d_in[2];
    const float* t1w   = (const float*)d_in[3];
    const float* t1b   = (const float*)d_in[4];
    const float* t2w   = (const float*)d_in[5];
    const float* t2b   = (const float*)d_in[6];
    const float* W1    = (const float*)d_in[7];
    const float* b1    = (const float*)d_in[8];
    const float* gamma = (const float*)d_in[9];
    const float* beta  = (const float*)d_in[10];
    const float* W2    = (const float*)d_in[11];
    const float* b2    = (const float*)d_in[12];
    float* out = (float*)d_out;

    char* ws = (char*)d_ws;
    size_t off_b = 0;
    auto alloc = [&](size_t bytes) -> void* {
        off_b = (off_b + 511) & ~size_t(511);
        void* p = ws + off_b;
        off_b += bytes;
        return p;
    };
    unsigned short* hbA = (unsigned short*)alloc((size_t)NR * 128 * 2);
    unsigned short* zb  = (unsigned short*)alloc((size_t)NR * 128 * 2);
    unsigned short* Wb  = (unsigned short*)alloc((size_t)131072 * 2);
    int* rowptr         = (int*)alloc((size_t)(NNODES + 2) * 4);
    int* ghist          = (int*)alloc((size_t)NB * NBLK_BIN * 4);
    int* off            = (int*)alloc((size_t)NB * NBLK_BIN * 4);
    int* tot            = (int*)alloc((size_t)NB * 4);
    int* boff           = (int*)alloc((size_t)(NB + 1) * 4);
    unsigned int* binned = (unsigned int*)alloc((size_t)NEDGES * 4);
    int* csr            = (int*)alloc((size_t)NEDGES * 4);

    const int* esrc = ei;
    const int* edst = ei + NEDGES;

    // weights -> bf16
    wconv<<<128, 256, 0, stream>>>(t1w, t2w, W1, W2, Wb);

    // two-pass partition + CSR build (no global atomics)
    hist_k<<<NBLK_BIN, 256, 0, stream>>>(edst, ghist);
    scan_pairs<<<(NB + 3) / 4, 256, 0, stream>>>(ghist, off, tot);
    boff_scan<<<1, 1024, 0, stream>>>(tot, boff);
    scatter2<<<NBLK_BIN, 256, 0, stream>>>(esrc, edst, off, boff, binned);
    csr_build<<<NB, 256, 0, stream>>>(boff, binned, rowptr, csr);

    // h = relu(x @ t1_w^T + t1_b) -> hbA
    gemm128<1, 1><<<NR / 128, 256, 0, stream>>>(x, NNODES, Wb, t1b, hbA);

    // 3 GIN layers: gather (standalone, high-occupancy) + fused MLP
    for (int l = 0; l < 3; ++l) {
        agg_node4<<<25000, 256, 0, stream>>>(hbA, rowptr, csr, zb);
        mlp128<<<NB, 512, 0, stream>>>(zb,
                                       Wb + 32768 + (size_t)l * 16384,
                                       Wb + 81920 + (size_t)l * 16384,
                                       b1 + l * 128, gamma + l * 128, beta + l * 128,
                                       b2 + l * 128, hbA);
    }
    // final transform + graph pooling
    gemm128<0, 0><<<NR / 128, 256, 0, stream>>>(hbA, NR, Wb + 16384, t2b, zb);
    segsum<<<NGRAPH, 128, 0, stream>>>(zb, batch, out);
}